// Round 17
// baseline (133.209 us; speedup 1.0000x reference)
//
#include <hip/hip_runtime.h>
#include <hip/hip_fp8.h>
#include <cstdint>
#include <cstddef>

typedef __bf16 bf16;
typedef __attribute__((ext_vector_type(8))) __bf16 bf16x8;
typedef __attribute__((ext_vector_type(4))) float f32x4;
typedef __attribute__((ext_vector_type(4))) unsigned short u16x4;
typedef __attribute__((ext_vector_type(8))) unsigned short u16x8;
typedef __attribute__((ext_vector_type(16))) unsigned char u8x16;
typedef __attribute__((ext_vector_type(2))) long long llx2;

#define DEV __device__ __forceinline__

// fp32 -> bf16 round-to-nearest-even (explicit, deterministic)
DEV unsigned short f2bf(float f) {
    unsigned int u = __builtin_bit_cast(unsigned int, f);
    u += 0x7FFFu + ((u >> 16) & 1u);
    return (unsigned short)(u >> 16);
}

DEV float bf2f(unsigned short h) {
    unsigned int u = ((unsigned int)h) << 16;
    return __builtin_bit_cast(float, u);
}

// fp32 -> fp8 e4m3 (OCP), RNE+satfinite via HIP type
DEV unsigned char f2e4m3(float f) {
    __hip_fp8_e4m3 t(f);
    return (unsigned char)t.__x;
}

// async global->LDS, 16B per lane; lds base must be wave-uniform (HW adds lane*16)
DEV void gload16(const void* g, void* l) {
    __builtin_amdgcn_global_load_lds(
        (const __attribute__((address_space(1))) unsigned int*)g,
        (__attribute__((address_space(3))) unsigned int*)l, 16, 0, 0);
}

DEV f32x4 mfma16(bf16x8 a, bf16x8 b, f32x4 c) {
    return __builtin_amdgcn_mfma_f32_16x16x32_bf16(a, b, c, 0, 0, 0);
}

DEV f32x4 mfma8(long long a, long long b, f32x4 c) {
    return __builtin_amdgcn_mfma_f32_16x16x32_fp8_fp8(a, b, c, 0, 0, 0);
}

// ---------------------------------------------------------------------------
// K0: fused weight conversion + GroupNorm stats.
// blocks [0,1024): weight conversion — q-rows AND k-rows get
//   sqrt((1/16)*log2(e)) = 0.3002806 folded in; logits land in log2 domain.
// blocks [1024,1152): GroupNorm stats, one block per (b, group).
// ---------------------------------------------------------------------------
__global__ __launch_bounds__(256) void k_pre(const float* __restrict__ wqkv,
        const float* __restrict__ wproj, const float* __restrict__ x,
        unsigned short* __restrict__ wq, unsigned short* __restrict__ wp,
        float* __restrict__ stats) {
    if (blockIdx.x < 1024) {
        int i = blockIdx.x * 256 + threadIdx.x;   // covers 768*256 + 256*256 exactly
        if (i < 768 * 256) {
            float v = wqkv[i];
            if (i < 512 * 256) v *= 0.3002806f;   // q and k rows
            wq[i] = f2bf(v);
        } else {
            int j = i - 768 * 256;
            wp[j] = f2bf(wproj[j]);
        }
        return;
    }
    int bg = blockIdx.x - 1024;  // b*32 + g
    const float4* xp = (const float4*)(x + (size_t)bg * 32768);
    int t = threadIdx.x;
    float s = 0.f, sq = 0.f;
    #pragma unroll 4
    for (int i = 0; i < 32; ++i) {
        float4 v = xp[t + i * 256];
        s  += v.x + v.y + v.z + v.w;
        sq += v.x * v.x + v.y * v.y + v.z * v.z + v.w * v.w;
    }
    #pragma unroll
    for (int m = 1; m < 64; m <<= 1) { s += __shfl_xor(s, m); sq += __shfl_xor(sq, m); }
    __shared__ float red[8];
    int w = t >> 6;
    if ((t & 63) == 0) { red[w] = s; red[4 + w] = sq; }
    __syncthreads();
    if (t == 0) {
        s  = red[0] + red[1] + red[2] + red[3];
        sq = red[4] + red[5] + red[6] + red[7];
        float mean = s * (1.f / 32768.f);
        float var  = sq * (1.f / 32768.f) - mean * mean;
        stats[bg * 2]     = mean;
        stats[bg * 2 + 1] = rsqrtf(var + 1e-5f);
    }
}

// ---------------------------------------------------------------------------
// K2: apply GroupNorm -> xnT bf16 (b,n,c) only (residual recomputed in k_proj).
// ---------------------------------------------------------------------------
__global__ __launch_bounds__(256) void k_gnapply(const float* __restrict__ x,
        const float* __restrict__ scale, const float* __restrict__ bias,
        const float* __restrict__ stats, unsigned short* __restrict__ xnT) {
    __shared__ __align__(16) unsigned short tsm[64][72];
    int t = threadIdx.x;
    int nb = blockIdx.x * 64, cb = blockIdx.y * 64, b = blockIdx.z;
    int cl = t >> 2, nc = (t & 3) * 16;
    int cg = cb + cl;
    float mean = stats[(b * 32 + (cg >> 3)) * 2];
    float rstd = stats[(b * 32 + (cg >> 3)) * 2 + 1];
    float sc = scale[cg] * rstd;
    float bi = bias[cg] - mean * sc;      // xn = x*sc + bi
    const float4* xrow = (const float4*)(x + ((size_t)(b * 256 + cg)) * 4096 + nb + nc);
    #pragma unroll
    for (int j = 0; j < 4; ++j) {
        float4 v = xrow[j];
        u16x4 us;
        us[0] = f2bf(v.x * sc + bi); us[1] = f2bf(v.y * sc + bi);
        us[2] = f2bf(v.z * sc + bi); us[3] = f2bf(v.w * sc + bi);
        *(u16x4*)&tsm[cl][nc + j * 4] = us;
    }
    __syncthreads();
    int nl = t >> 2, cc = (t & 3) * 16;
    u16x8 o0, o1;
    #pragma unroll
    for (int j = 0; j < 8; ++j) { o0[j] = tsm[cc + j][nl]; o1[j] = tsm[cc + 8 + j][nl]; }
    unsigned short* dst = xnT + ((size_t)(b * 4096 + nb + nl)) * 256 + cb + cc;
    *(u16x8*)dst = o0;
    *(u16x8*)(dst + 8) = o1;
}

// ---------------------------------------------------------------------------
// K3: QKV GEMM, ALL-N per block. Grid (256): block owns m-tile mb=bid*64,
// stages its A-tile (64x256) ONCE, loads af once, and loops over all 12
// B-tiles with double-buffered Bsm (prefetch nt+1 while computing nt; the
// end-of-iter barrier both drains the prefetch and releases the old buffer).
// nt<8 -> q/k fp8 out; nt>=8 -> v (fp8, PERMUTED layout for attn):
//   vT8[b][d][tile64][chunk g: kv {g*8..+8} then {32+g*8..+8}]  (16B chunks)
// A-traffic drops 48MB -> 8MB (xnT read once); B stays L2-resident.
// ---------------------------------------------------------------------------
__global__ __launch_bounds__(256) void k_qkv(const unsigned short* __restrict__ xnT,
        const unsigned short* __restrict__ wq, unsigned char* __restrict__ qk8,
        unsigned char* __restrict__ vT8) {
    __shared__ __align__(16) char smem[107520];  // Asm 32K | Bsm0 32K | Bsm1 32K | tsm 9K
    char* Asm = smem;
    char* Bsm0 = smem + 32768;
    char* Bsm1 = smem + 65536;
    unsigned short (*tsm)[72] = (unsigned short (*)[72])(smem + 98304);
    int t = threadIdx.x, l = t & 63, w = t >> 6;
    int mb = blockIdx.x * 64;
    // stage A once
    #pragma unroll
    for (int i = 0; i < 8; ++i) {
        int idx = (w * 8 + i) * 64 + l;
        int r = idx >> 5, p = idx & 31;
        gload16(xnT + (size_t)(mb + r) * 256 + ((p ^ (r & 7)) * 8), Asm + (w * 8 + i) * 1024);
    }
    // stage B tile 0
    #pragma unroll
    for (int i = 0; i < 8; ++i) {
        int idx = (w * 8 + i) * 64 + l;
        int r = idx >> 5, p = idx & 31;
        gload16(wq + (size_t)r * 256 + ((p ^ (r & 7)) * 8), Bsm0 + (w * 8 + i) * 1024);
    }
    __syncthreads();
    int arow = w * 16 + (l & 15);
    bf16x8 af[8];
    #pragma unroll
    for (int ks = 0; ks < 8; ++ks)
        af[ks] = *(const bf16x8*)(Asm + arow * 512 + (((ks * 4 + (l >> 4)) ^ (arow & 7)) << 4));
    int row0 = mb + w * 16 + (l >> 4) * 4;
    int b = mb >> 12;
    int nloc = mb & 4095;

    for (int nt = 0; nt < 12; ++nt) {
        char* Bcur = (nt & 1) ? Bsm1 : Bsm0;
        char* Bnxt = (nt & 1) ? Bsm0 : Bsm1;
        if (nt + 1 < 12) {       // prefetch next B (old buffer released by last barrier)
            #pragma unroll
            for (int i = 0; i < 8; ++i) {
                int idx = (w * 8 + i) * 64 + l;
                int r = idx >> 5, p = idx & 31;
                gload16(wq + (size_t)((nt + 1) * 64 + r) * 256 + ((p ^ (r & 7)) * 8),
                        Bnxt + (w * 8 + i) * 1024);
            }
        }
        int nb = nt * 64;
        f32x4 acc[4];
        #pragma unroll
        for (int i = 0; i < 4; ++i) acc[i] = f32x4{0.f, 0.f, 0.f, 0.f};
        #pragma unroll
        for (int sub = 0; sub < 4; ++sub) {
            int brow = sub * 16 + (l & 15);
            #pragma unroll
            for (int ks = 0; ks < 8; ++ks) {
                bf16x8 bb = *(const bf16x8*)(Bcur + brow * 512 + (((ks * 4 + (l >> 4)) ^ (brow & 7)) << 4));
                acc[sub] = mfma16(af[ks], bb, acc[sub]);
            }
        }
        if (nt < 8) {
            #pragma unroll
            for (int sub = 0; sub < 4; ++sub) {
                #pragma unroll
                for (int r = 0; r < 4; ++r)
                    qk8[(size_t)(row0 + r) * 512 + nb + sub * 16 + (l & 15)] = f2e4m3(acc[sub][r]);
            }
        } else {
            // fused V transpose: acc -> tsm [n][c] -> fp8 permuted vT8
            int rt = w * 16 + (l >> 4) * 4;           // n-row in tile
            #pragma unroll
            for (int sub = 0; sub < 4; ++sub) {
                int ct = sub * 16 + (l & 15);         // c-col in tile
                #pragma unroll
                for (int r = 0; r < 4; ++r)
                    tsm[rt + r][ct] = f2bf(acc[sub][r]);
            }
            __syncthreads();
            int clc = t >> 2, g = t & 3;
            u8x16 ob;
            #pragma unroll
            for (int j = 0; j < 8; ++j) {
                ob[j]     = f2e4m3(bf2f(tsm[g * 8 + j][clc]));        // js=0: kv g*8+j
                ob[8 + j] = f2e4m3(bf2f(tsm[32 + g * 8 + j][clc]));   // js=1: kv 32+g*8+j
            }
            int d = (nb - 512) + clc;
            unsigned char* dst = vT8 + ((size_t)(b * 256 + d)) * 4096 + nloc + g * 16;
            *(u8x16*)dst = ob;
        }
        __syncthreads();   // next-B staged (vmcnt drained); Bcur & tsm released
    }
}

// ---------------------------------------------------------------------------
// K5: flash attention (R16-proven): fp8 QK^T + fp8 P·V with d-paired 128B
// V rows (8 chunk-XOR positions) and js-paired b128 reads (one read feeds
// two MFMAs). P fp8 16x64 per wave. 8 waves x 16 q-rows, KVBLK=64,
// kv-split x2, dbuf, 1 barrier/tile, row-sum via fp8 ones-MFMA, defer-max
// THR=8 (P <= 256 < e4m3 max 448).
// LDS 72KB: K0@0(16K), V0@16K(16K), K1@32K, V1@48K, P@64K (8 x 1KB).
// ---------------------------------------------------------------------------
struct AttnState {
    f32x4 acc[16];
    f32x4 accSum;
    float m_run[4];
};

DEV void attn_compute(const char* Ksm, const char* Vsm, char* Psm,
                      const long long qf8[8], AttnState& st, int l) {
    // S = Q·K^T, fp8 x fp8 (log2 domain)
    f32x4 s[4];
    __builtin_amdgcn_s_setprio(1);
    #pragma unroll
    for (int jt = 0; jt < 4; ++jt) {
        f32x4 a = f32x4{0.f, 0.f, 0.f, 0.f};
        int jr = jt * 16 + (l & 15);
        #pragma unroll
        for (int ks = 0; ks < 8; ++ks) {
            int c8 = ks * 4 + (l >> 4);
            long long kb = *(const long long*)(Ksm + jr * 256 +
                            (((c8 >> 1) ^ (jr & 7)) << 4) + (c8 & 1) * 8);
            a = mfma8(qf8[ks], kb, a);
        }
        s[jt] = a;
    }
    __builtin_amdgcn_s_setprio(0);

    // tile max (16-lane reduce per row)
    float tm[4];
    #pragma unroll
    for (int r = 0; r < 4; ++r) {
        float v = fmaxf(fmaxf(s[0][r], s[1][r]), fmaxf(s[2][r], s[3][r]));
        #pragma unroll
        for (int mm = 1; mm < 16; mm <<= 1) v = fmaxf(v, __shfl_xor(v, mm));
        tm[r] = v;
    }
    int defer = 1;
    #pragma unroll
    for (int r = 0; r < 4; ++r) defer &= (tm[r] <= st.m_run[r] + 8.f) ? 1 : 0;
    bool alldef = __all(defer);
    if (!alldef) {
        float sf[4];
        #pragma unroll
        for (int r = 0; r < 4; ++r) {
            float mn = fmaxf(st.m_run[r], tm[r]);
            sf[r] = __builtin_amdgcn_exp2f(st.m_run[r] - mn);
            st.m_run[r] = mn;
        }
        #pragma unroll
        for (int i = 0; i < 16; ++i) {
            st.acc[i][0] *= sf[0]; st.acc[i][1] *= sf[1];
            st.acc[i][2] *= sf[2]; st.acc[i][3] *= sf[3];
        }
        st.accSum[0] *= sf[0]; st.accSum[1] *= sf[1];
        st.accSum[2] *= sf[2]; st.accSum[3] *= sf[3];
    }

    // P = exp2(S - m) -> fp8 in per-wave LDS: 16 rows x 64B, chunk g packs
    // js0|js1 pieces; chunk XOR key = (row>>1)&3.
    #pragma unroll
    for (int jt = 0; jt < 4; ++jt) {
        #pragma unroll
        for (int r = 0; r < 4; ++r) {
            float pv = __builtin_amdgcn_exp2f(s[jt][r] - st.m_run[r]);
            int row = (l >> 4) * 4 + r;
            int j = jt * 16 + (l & 15);
            int g = (j >> 3) & 3, js = j >> 5;
            int bo = row * 64 + (((g ^ ((row >> 1) & 3))) << 4) + js * 8 + (j & 7);
            *(unsigned char*)(Psm + bo) = f2e4m3(pv);
        }
    }
    asm volatile("s_waitcnt lgkmcnt(0)" ::: "memory");
    __builtin_amdgcn_sched_barrier(0);

    // O += P · V (fp8): one b128 per operand pair feeds two MFMAs (js=0,1).
    const long long ones8 = 0x3838383838383838LL;   // e4m3 1.0 x8
    __builtin_amdgcn_s_setprio(1);
    {
        int pr = l & 15;
        llx2 pa01 = *(const llx2*)(Psm + pr * 64 +
                     ((((l >> 4)) ^ ((pr >> 1) & 3)) << 4));
        #pragma unroll
        for (int sub = 0; sub < 16; ++sub) {
            int d = sub * 16 + (l & 15);
            int dp = d >> 1, h = d & 1;
            llx2 vb01 = *(const llx2*)(Vsm + dp * 128 +
                         ((h * 4 + ((l >> 4) ^ (dp & 3))) << 4));
            st.acc[sub] = mfma8(pa01[0], vb01[0], st.acc[sub]);
            st.acc[sub] = mfma8(pa01[1], vb01[1], st.acc[sub]);
        }
        st.accSum = mfma8(pa01[0], ones8, st.accSum);
        st.accSum = mfma8(pa01[1], ones8, st.accSum);
    }
    __builtin_amdgcn_s_setprio(0);
}

#define ATTN_STAGE(KN, VN, kvn)                                                   \
    do {                                                                          \
        _Pragma("unroll")                                                         \
        for (int i_ = 0; i_ < 2; ++i_) {      /* K fp8: 16KB, rows 256B */        \
            int e_ = (w * 2 + i_) * 64 + l;                                       \
            int r_ = e_ >> 4, p_ = e_ & 15;                                       \
            gload16(kg8 + (size_t)((kvn) + r_) * 512 + ((p_ ^ (r_ & 7)) * 16),    \
                    (KN) + (w * 2 + i_) * 1024);                                  \
        }                                                                         \
        _Pragma("unroll")                                                         \
        for (int i_ = 0; i_ < 2; ++i_) {      /* V fp8: 16KB, d-paired 128B */    \
            int e_ = (w * 2 + i_) * 64 + l;                                       \
            int dp_ = e_ >> 3, c_ = e_ & 7;                                       \
            int h_ = c_ >> 2, g_ = (c_ & 3) ^ (dp_ & 3);                          \
            gload16(vg8 + (size_t)(2 * dp_ + h_) * 4096 + (kvn) + g_ * 16,        \
                    (VN) + (w * 2 + i_) * 1024);                                  \
        }                                                                         \
    } while (0)

__global__ __launch_bounds__(512, 2) void k_attn(const unsigned char* __restrict__ qk8,
        const unsigned char* __restrict__ vT8, unsigned short* __restrict__ Opart,
        float* __restrict__ ml) {
    __shared__ __align__(16) char smem[73728];
    char* Ksm0 = smem;
    char* Vsm0 = smem + 16384;
    char* Ksm1 = smem + 32768;
    char* Vsm1 = smem + 49152;
    int t = threadIdx.x, l = t & 63, w = t >> 6;   // w in 0..7
    char* Psm = smem + 65536 + w * 1024;           // per-wave P 16x64 fp8
    int bid = blockIdx.x;
    int combo = bid & 7;
    int b = combo >> 1;
    int half = combo & 1;
    int qb = (bid >> 3) * 128;
    int kv0 = half * 2048;

    const unsigned char* qrow8 = qk8 + (size_t)(b * 4096 + qb + w * 16 + (l & 15)) * 512;
    long long qf8[8];
    #pragma unroll
    for (int ks = 0; ks < 8; ++ks)
        qf8[ks] = *(const long long*)(qrow8 + ks * 32 + (l >> 4) * 8);

    AttnState st;
    #pragma unroll
    for (int i = 0; i < 16; ++i) st.acc[i] = f32x4{0.f, 0.f, 0.f, 0.f};
    st.accSum = f32x4{0.f, 0.f, 0.f, 0.f};
    #pragma unroll
    for (int r = 0; r < 4; ++r) st.m_run[r] = -3.0e38f;

    const unsigned char* kg8 = qk8 + (size_t)(b * 4096) * 512 + 256;
    const unsigned char* vg8 = vT8 + (size_t)(b * 256) * 4096;

    ATTN_STAGE(Ksm0, Vsm0, kv0);
    __syncthreads();

    for (int kv = kv0; kv < kv0 + 2048; kv += 128) {
        ATTN_STAGE(Ksm1, Vsm1, kv + 64);
        attn_compute(Ksm0, Vsm0, Psm, qf8, st, l);
        __syncthreads();   // buf1 staged; buf0 reads done block-wide
        int kvn2 = (kv + 128 < kv0 + 2048) ? (kv + 128) : kv0;  // last: harmless re-stage
        ATTN_STAGE(Ksm0, Vsm0, kvn2);
        attn_compute(Ksm1, Vsm1, Psm, qf8, st, l);
        __syncthreads();
    }

    float inv[4];
    #pragma unroll
    for (int r = 0; r < 4; ++r) inv[r] = 1.f / st.accSum[r];
    unsigned short* orow = Opart + (size_t)half * 16384 * 256 +
                           (size_t)(b * 4096 + qb + w * 16) * 256;
    #pragma unroll
    for (int sub = 0; sub < 16; ++sub) {
        #pragma unroll
        for (int r = 0; r < 4; ++r)
            orow[(size_t)((l >> 4) * 4 + r) * 256 + sub * 16 + (l & 15)] = f2bf(st.acc[sub][r] * inv[r]);
    }
    if ((l & 15) == 0) {
        size_t mlbase = (size_t)(b * 4096 + qb + w * 16 + (l >> 4) * 4) * 4;
        #pragma unroll
        for (int r = 0; r < 4; ++r) {
            ml[mlbase + (size_t)r * 4 + half * 2]     = st.m_run[r];
            ml[mlbase + (size_t)r * 4 + half * 2 + 1] = st.accSum[r];
        }
    }
}

// ---------------------------------------------------------------------------
// K6: proj GEMM + FUSED kv-half combine + bias + residual (recomputed GN).
// ---------------------------------------------------------------------------
__global__ __launch_bounds__(256) void k_proj(const unsigned short* __restrict__ Opart,
        const float* __restrict__ ml, const unsigned short* __restrict__ wp,
        const float* __restrict__ bproj, const float* __restrict__ x,
        const float* __restrict__ nscale, const float* __restrict__ nbias,
        const float* __restrict__ stats, float* __restrict__ out) {
    __shared__ __align__(16) char smem[65536];
    char* Asm = smem;
    char* Bsm = smem + 32768;
    int t = threadIdx.x, l = t & 63, w = t >> 6;
    int mb = blockIdx.x * 64, nb = blockIdx.y * 64;
    #pragma unroll
    for (int i = 0; i < 8; ++i) {
        int idx = (w * 8 + i) * 64 + l;
        int r = idx >> 5, p = idx & 31;
        size_t grow = (size_t)(mb + r);
        const u16x8* o1p = (const u16x8*)(Opart + grow * 256 + ((p ^ (r & 7)) * 8));
        const u16x8* o2p = (const u16x8*)((const unsigned short*)o1p + (size_t)16384 * 256);
        float m1 = ml[grow * 4],     l1 = ml[grow * 4 + 1];
        float m2 = ml[grow * 4 + 2], l2 = ml[grow * 4 + 3];
        float m = fmaxf(m1, m2);
        float a1 = __builtin_amdgcn_exp2f(m1 - m) * l1;
        float a2 = __builtin_amdgcn_exp2f(m2 - m) * l2;
        float zinv = 1.f / (a1 + a2);
        float w1 = a1 * zinv, w2 = a2 * zinv;
        u16x8 o1 = *o1p, o2 = *o2p, a;
        #pragma unroll
        for (int j = 0; j < 8; ++j) a[j] = f2bf(w1 * bf2f(o1[j]) + w2 * bf2f(o2[j]));
        *(u16x8*)(Asm + (w * 8 + i) * 1024 + l * 16) = a;
    }
    #pragma unroll
    for (int i = 0; i < 8; ++i) {
        int idx = (w * 8 + i) * 64 + l;
        int r = idx >> 5, p = idx & 31;
        gload16(wp + (size_t)(nb + r) * 256 + ((p ^ (r & 7)) * 8), Bsm + (w * 8 + i) * 1024);
    }
    __syncthreads();
    int arow = w * 16 + (l & 15);
    bf16x8 af[8];
    #pragma unroll
    for (int ks = 0; ks < 8; ++ks)
        af[ks] = *(const bf16x8*)(Asm + arow * 512 + (((ks * 4 + (l >> 4)) ^ (arow & 7)) << 4));
    f32x4 acc[4];
    #pragma unroll
    for (int i = 0; i < 4; ++i) acc[i] = f32x4{0.f, 0.f, 0.f, 0.f};
    #pragma unroll
    for (int sub = 0; sub < 4; ++sub) {
        int brow = sub * 16 + (l & 15);
        #pragma unroll
        for (int ks = 0; ks < 8; ++ks) {
            bf16x8 bb = *(const bf16x8*)(Bsm + brow * 512 + (((ks * 4 + (l >> 4)) ^ (brow & 7)) << 4));
            acc[sub] = mfma16(af[ks], bb, acc[sub]);
        }
    }
    __syncthreads();  // all waves done reading A/B tiles; reuse LDS for transpose
    float* tr = (float*)smem;  // [64][68] f32
    #pragma unroll
    for (int sub = 0; sub < 4; ++sub) {
        int o = sub * 16 + (l & 15);
        *(f32x4*)(tr + o * 68 + w * 16 + (l >> 4) * 4) = acc[sub];
    }
    __syncthreads();
    int b = mb >> 12;
    int nloc = mb & 4095;
    #pragma unroll
    for (int it = 0; it < 4; ++it) {
        int e = it * 256 + t;
        int o = e >> 4, m4 = (e & 15) * 4;
        f32x4 v = *(const f32x4*)(tr + o * 68 + m4);
        int c = nb + o;
        float bv = bproj[c];
        float mean = stats[(b * 32 + (c >> 3)) * 2];
        float rstd = stats[(b * 32 + (c >> 3)) * 2 + 1];
        float sc = nscale[c] * rstd;
        float bi = nbias[c] - mean * sc;
        size_t off = ((size_t)(b * 256 + c)) * 4096 + nloc + m4;
        float4 xx = *(const float4*)(x + off);
        float4 ov;
        ov.x = v[0] + bv + (xx.x * sc + bi);
        ov.y = v[1] + bv + (xx.y * sc + bi);
        ov.z = v[2] + bv + (xx.z * sc + bi);
        ov.w = v[3] + bv + (xx.w * sc + bi);
        *(float4*)(out + off) = ov;
    }
}

// ---------------------------------------------------------------------------
extern "C" void kernel_launch(void* const* d_in, const int* in_sizes, int n_in,
                              void* d_out, int out_size, void* d_ws, size_t ws_size,
                              hipStream_t stream) {
    const float* x      = (const float*)d_in[0];
    const float* nscale = (const float*)d_in[1];
    const float* nbias  = (const float*)d_in[2];
    const float* wqkv   = (const float*)d_in[3];
    const float* wproj  = (const float*)d_in[4];
    const float* bproj  = (const float*)d_in[5];
    float* out = (float*)d_out;

    char* ws = (char*)d_ws;
    float* stats = (float*)ws;                                        // 4 KB
    unsigned short* xnT = (unsigned short*)(ws + 4096);               // 8 MB bf16 (b,n,c)
    unsigned short* wq  = xnT + 4194304;                              // 384 KB
    unsigned short* wp  = wq + 768 * 256;                             // 128 KB
    unsigned char* vT8  = (unsigned char*)(wp + 256 * 256);           // 4 MB fp8 (b,d,perm-kv)
    float* ml = (float*)(vT8 + (size_t)4 * 256 * 4096);               // 256 KB
    unsigned char* qk8 = (unsigned char*)(ml + 65536);                // 8 MB fp8 (b,n,512): q|k
    unsigned short* Opart = (unsigned short*)(qk8 + (size_t)16384 * 512); // 16 MB bf16 (2,16384,256)

    hipLaunchKernelGGL(k_pre,     dim3(1152),       dim3(256), 0, stream, wqkv, wproj, x, wq, wp, stats);
    hipLaunchKernelGGL(k_gnapply, dim3(64, 4, 4),   dim3(256), 0, stream, x, nscale, nbias, stats, xnT);
    hipLaunchKernelGGL(k_qkv,     dim3(256),        dim3(256), 0, stream, xnT, wq, qk8, vT8);
    hipLaunchKernelGGL(k_attn,    dim3(256),        dim3(512), 0, stream, qk8, vT8, Opart, ml);
    hipLaunchKernelGGL(k_proj,    dim3(256, 4),     dim3(256), 0, stream, Opart, ml, wp, bproj, x, nscale, nbias, stats, out);
}

// Round 18
// 128.983 us; speedup vs baseline: 1.0328x; 1.0328x over previous
//
#include <hip/hip_runtime.h>
#include <hip/hip_fp8.h>
#include <cstdint>
#include <cstddef>

typedef __bf16 bf16;
typedef __attribute__((ext_vector_type(8))) __bf16 bf16x8;
typedef __attribute__((ext_vector_type(4))) float f32x4;
typedef __attribute__((ext_vector_type(4))) unsigned short u16x4;
typedef __attribute__((ext_vector_type(8))) unsigned short u16x8;
typedef __attribute__((ext_vector_type(16))) unsigned char u8x16;
typedef __attribute__((ext_vector_type(2))) long long llx2;

#define DEV __device__ __forceinline__

// fp32 -> bf16 round-to-nearest-even (explicit, deterministic)
DEV unsigned short f2bf(float f) {
    unsigned int u = __builtin_bit_cast(unsigned int, f);
    u += 0x7FFFu + ((u >> 16) & 1u);
    return (unsigned short)(u >> 16);
}

DEV float bf2f(unsigned short h) {
    unsigned int u = ((unsigned int)h) << 16;
    return __builtin_bit_cast(float, u);
}

// fp32 -> fp8 e4m3 (OCP), RNE+satfinite via HIP type
DEV unsigned char f2e4m3(float f) {
    __hip_fp8_e4m3 t(f);
    return (unsigned char)t.__x;
}

// async global->LDS, 16B per lane; lds base must be wave-uniform (HW adds lane*16)
DEV void gload16(const void* g, void* l) {
    __builtin_amdgcn_global_load_lds(
        (const __attribute__((address_space(1))) unsigned int*)g,
        (__attribute__((address_space(3))) unsigned int*)l, 16, 0, 0);
}

DEV f32x4 mfma16(bf16x8 a, bf16x8 b, f32x4 c) {
    return __builtin_amdgcn_mfma_f32_16x16x32_bf16(a, b, c, 0, 0, 0);
}

DEV f32x4 mfma8(long long a, long long b, f32x4 c) {
    return __builtin_amdgcn_mfma_f32_16x16x32_fp8_fp8(a, b, c, 0, 0, 0);
}

// ---------------------------------------------------------------------------
// K0: fused weight conversion + GroupNorm stats.
// blocks [0,1024): weight conversion — q-rows AND k-rows get
//   sqrt((1/16)*log2(e)) = 0.3002806 folded in; logits land in log2 domain.
// blocks [1024,1152): GroupNorm stats, one block per (b, group).
// ---------------------------------------------------------------------------
__global__ __launch_bounds__(256) void k_pre(const float* __restrict__ wqkv,
        const float* __restrict__ wproj, const float* __restrict__ x,
        unsigned short* __restrict__ wq, unsigned short* __restrict__ wp,
        float* __restrict__ stats) {
    if (blockIdx.x < 1024) {
        int i = blockIdx.x * 256 + threadIdx.x;   // covers 768*256 + 256*256 exactly
        if (i < 768 * 256) {
            float v = wqkv[i];
            if (i < 512 * 256) v *= 0.3002806f;   // q and k rows
            wq[i] = f2bf(v);
        } else {
            int j = i - 768 * 256;
            wp[j] = f2bf(wproj[j]);
        }
        return;
    }
    int bg = blockIdx.x - 1024;  // b*32 + g
    const float4* xp = (const float4*)(x + (size_t)bg * 32768);
    int t = threadIdx.x;
    float s = 0.f, sq = 0.f;
    #pragma unroll 4
    for (int i = 0; i < 32; ++i) {
        float4 v = xp[t + i * 256];
        s  += v.x + v.y + v.z + v.w;
        sq += v.x * v.x + v.y * v.y + v.z * v.z + v.w * v.w;
    }
    #pragma unroll
    for (int m = 1; m < 64; m <<= 1) { s += __shfl_xor(s, m); sq += __shfl_xor(sq, m); }
    __shared__ float red[8];
    int w = t >> 6;
    if ((t & 63) == 0) { red[w] = s; red[4 + w] = sq; }
    __syncthreads();
    if (t == 0) {
        s  = red[0] + red[1] + red[2] + red[3];
        sq = red[4] + red[5] + red[6] + red[7];
        float mean = s * (1.f / 32768.f);
        float var  = sq * (1.f / 32768.f) - mean * mean;
        stats[bg * 2]     = mean;
        stats[bg * 2 + 1] = rsqrtf(var + 1e-5f);
    }
}

// ---------------------------------------------------------------------------
// K2: apply GroupNorm -> xnT bf16 (b,n,c) only (residual recomputed in k_proj).
// ---------------------------------------------------------------------------
__global__ __launch_bounds__(256) void k_gnapply(const float* __restrict__ x,
        const float* __restrict__ scale, const float* __restrict__ bias,
        const float* __restrict__ stats, unsigned short* __restrict__ xnT) {
    __shared__ __align__(16) unsigned short tsm[64][72];
    int t = threadIdx.x;
    int nb = blockIdx.x * 64, cb = blockIdx.y * 64, b = blockIdx.z;
    int cl = t >> 2, nc = (t & 3) * 16;
    int cg = cb + cl;
    float mean = stats[(b * 32 + (cg >> 3)) * 2];
    float rstd = stats[(b * 32 + (cg >> 3)) * 2 + 1];
    float sc = scale[cg] * rstd;
    float bi = bias[cg] - mean * sc;      // xn = x*sc + bi
    const float4* xrow = (const float4*)(x + ((size_t)(b * 256 + cg)) * 4096 + nb + nc);
    #pragma unroll
    for (int j = 0; j < 4; ++j) {
        float4 v = xrow[j];
        u16x4 us;
        us[0] = f2bf(v.x * sc + bi); us[1] = f2bf(v.y * sc + bi);
        us[2] = f2bf(v.z * sc + bi); us[3] = f2bf(v.w * sc + bi);
        *(u16x4*)&tsm[cl][nc + j * 4] = us;
    }
    __syncthreads();
    int nl = t >> 2, cc = (t & 3) * 16;
    u16x8 o0, o1;
    #pragma unroll
    for (int j = 0; j < 8; ++j) { o0[j] = tsm[cc + j][nl]; o1[j] = tsm[cc + 8 + j][nl]; }
    unsigned short* dst = xnT + ((size_t)(b * 4096 + nb + nl)) * 256 + cb + cc;
    *(u16x8*)dst = o0;
    *(u16x8*)(dst + 8) = o1;
}

// ---------------------------------------------------------------------------
// K3: QKV GEMM, dual-N-tile + fused V transpose. 64x128 output per block:
// A-tile staged once, af fragments reused across both B-tiles.
// Grid (256, 6): y<4 -> q/k (fp8 out), y>=4 -> v (fp8, PERMUTED layout):
//   vT8[b][d][tile64][chunk g: kv {g*8..+8} then {32+g*8..+8}]  (16B chunks)
// so attention can stage d-paired 128B LDS rows with js-paired 16B pieces.
// ---------------------------------------------------------------------------
__global__ __launch_bounds__(256) void k_qkv(const unsigned short* __restrict__ xnT,
        const unsigned short* __restrict__ wq, unsigned char* __restrict__ qk8,
        unsigned char* __restrict__ vT8) {
    __shared__ __align__(16) char smem[75776];   // Asm 32K | Bsm 32K | tsm 64x72x2
    char* Asm = smem;
    char* Bsm = smem + 32768;
    unsigned short (*tsm)[72] = (unsigned short (*)[72])(smem + 65536);
    int t = threadIdx.x, l = t & 63, w = t >> 6;
    int mb = blockIdx.x * 64;
    int nb0 = blockIdx.y * 128;
    // stage A once
    #pragma unroll
    for (int i = 0; i < 8; ++i) {
        int idx = (w * 8 + i) * 64 + l;
        int r = idx >> 5, p = idx & 31;
        gload16(xnT + (size_t)(mb + r) * 256 + ((p ^ (r & 7)) * 8), Asm + (w * 8 + i) * 1024);
    }
    // stage B half 0
    #pragma unroll
    for (int i = 0; i < 8; ++i) {
        int idx = (w * 8 + i) * 64 + l;
        int r = idx >> 5, p = idx & 31;
        gload16(wq + (size_t)(nb0 + r) * 256 + ((p ^ (r & 7)) * 8), Bsm + (w * 8 + i) * 1024);
    }
    __syncthreads();
    int arow = w * 16 + (l & 15);
    bf16x8 af[8];
    #pragma unroll
    for (int ks = 0; ks < 8; ++ks)
        af[ks] = *(const bf16x8*)(Asm + arow * 512 + (((ks * 4 + (l >> 4)) ^ (arow & 7)) << 4));
    int row0 = mb + w * 16 + (l >> 4) * 4;

    #pragma unroll
    for (int half = 0; half < 2; ++half) {
        int nb = nb0 + half * 64;
        f32x4 acc[4];
        #pragma unroll
        for (int i = 0; i < 4; ++i) acc[i] = f32x4{0.f, 0.f, 0.f, 0.f};
        #pragma unroll
        for (int sub = 0; sub < 4; ++sub) {
            int brow = sub * 16 + (l & 15);
            #pragma unroll
            for (int ks = 0; ks < 8; ++ks) {
                bf16x8 bb = *(const bf16x8*)(Bsm + brow * 512 + (((ks * 4 + (l >> 4)) ^ (brow & 7)) << 4));
                acc[sub] = mfma16(af[ks], bb, acc[sub]);
            }
        }
        if (nb < 512) {
            #pragma unroll
            for (int sub = 0; sub < 4; ++sub) {
                #pragma unroll
                for (int r = 0; r < 4; ++r)
                    qk8[(size_t)(row0 + r) * 512 + nb + sub * 16 + (l & 15)] = f2e4m3(acc[sub][r]);
            }
        } else {
            // fused V transpose: acc -> tsm [n][c] -> fp8 permuted vT8
            int rt = w * 16 + (l >> 4) * 4;           // n-row in tile
            #pragma unroll
            for (int sub = 0; sub < 4; ++sub) {
                int ct = sub * 16 + (l & 15);         // c-col in tile
                #pragma unroll
                for (int r = 0; r < 4; ++r)
                    tsm[rt + r][ct] = f2bf(acc[sub][r]);
            }
            __syncthreads();
            int clc = t >> 2, g = t & 3;
            u8x16 ob;
            #pragma unroll
            for (int j = 0; j < 8; ++j) {
                ob[j]     = f2e4m3(bf2f(tsm[g * 8 + j][clc]));        // js=0: kv g*8+j
                ob[8 + j] = f2e4m3(bf2f(tsm[32 + g * 8 + j][clc]));   // js=1: kv 32+g*8+j
            }
            int b = mb >> 12;
            int nloc = mb & 4095;   // 64-aligned tile base
            int d = (nb - 512) + clc;
            unsigned char* dst = vT8 + ((size_t)(b * 256 + d)) * 4096 + nloc + g * 16;
            *(u8x16*)dst = ob;
        }
        if (half == 0) {
            __syncthreads();   // all waves done with Bsm (and tsm if v)
            #pragma unroll
            for (int i = 0; i < 8; ++i) {
                int idx = (w * 8 + i) * 64 + l;
                int r = idx >> 5, p = idx & 31;
                gload16(wq + (size_t)(nb0 + 64 + r) * 256 + ((p ^ (r & 7)) * 8), Bsm + (w * 8 + i) * 1024);
            }
            __syncthreads();   // B half-1 visible
        }
    }
}

// ---------------------------------------------------------------------------
// K5: flash attention (R16-proven): fp8 QK^T + fp8 P·V with d-paired 128B
// V rows (8 chunk-XOR positions) and js-paired b128 reads (one read feeds
// two MFMAs). P fp8 16x64 per wave. 8 waves x 16 q-rows, KVBLK=64,
// kv-split x2, dbuf, 1 barrier/tile, row-sum via fp8 ones-MFMA, defer-max
// THR=8 (P <= 256 < e4m3 max 448).
// LDS 72KB: K0@0(16K), V0@16K(16K), K1@32K, V1@48K, P@64K (8 x 1KB).
// ---------------------------------------------------------------------------
struct AttnState {
    f32x4 acc[16];
    f32x4 accSum;
    float m_run[4];
};

DEV void attn_compute(const char* Ksm, const char* Vsm, char* Psm,
                      const long long qf8[8], AttnState& st, int l) {
    // S = Q·K^T, fp8 x fp8 (log2 domain)
    f32x4 s[4];
    __builtin_amdgcn_s_setprio(1);
    #pragma unroll
    for (int jt = 0; jt < 4; ++jt) {
        f32x4 a = f32x4{0.f, 0.f, 0.f, 0.f};
        int jr = jt * 16 + (l & 15);
        #pragma unroll
        for (int ks = 0; ks < 8; ++ks) {
            int c8 = ks * 4 + (l >> 4);
            long long kb = *(const long long*)(Ksm + jr * 256 +
                            (((c8 >> 1) ^ (jr & 7)) << 4) + (c8 & 1) * 8);
            a = mfma8(qf8[ks], kb, a);
        }
        s[jt] = a;
    }
    __builtin_amdgcn_s_setprio(0);

    // tile max (16-lane reduce per row)
    float tm[4];
    #pragma unroll
    for (int r = 0; r < 4; ++r) {
        float v = fmaxf(fmaxf(s[0][r], s[1][r]), fmaxf(s[2][r], s[3][r]));
        #pragma unroll
        for (int mm = 1; mm < 16; mm <<= 1) v = fmaxf(v, __shfl_xor(v, mm));
        tm[r] = v;
    }
    int defer = 1;
    #pragma unroll
    for (int r = 0; r < 4; ++r) defer &= (tm[r] <= st.m_run[r] + 8.f) ? 1 : 0;
    bool alldef = __all(defer);
    if (!alldef) {
        float sf[4];
        #pragma unroll
        for (int r = 0; r < 4; ++r) {
            float mn = fmaxf(st.m_run[r], tm[r]);
            sf[r] = __builtin_amdgcn_exp2f(st.m_run[r] - mn);
            st.m_run[r] = mn;
        }
        #pragma unroll
        for (int i = 0; i < 16; ++i) {
            st.acc[i][0] *= sf[0]; st.acc[i][1] *= sf[1];
            st.acc[i][2] *= sf[2]; st.acc[i][3] *= sf[3];
        }
        st.accSum[0] *= sf[0]; st.accSum[1] *= sf[1];
        st.accSum[2] *= sf[2]; st.accSum[3] *= sf[3];
    }

    // P = exp2(S - m) -> fp8 in per-wave LDS: 16 rows x 64B, chunk g packs
    // js0|js1 pieces; chunk XOR key = (row>>1)&3.
    #pragma unroll
    for (int jt = 0; jt < 4; ++jt) {
        #pragma unroll
        for (int r = 0; r < 4; ++r) {
            float pv = __builtin_amdgcn_exp2f(s[jt][r] - st.m_run[r]);
            int row = (l >> 4) * 4 + r;
            int j = jt * 16 + (l & 15);
            int g = (j >> 3) & 3, js = j >> 5;
            int bo = row * 64 + (((g ^ ((row >> 1) & 3))) << 4) + js * 8 + (j & 7);
            *(unsigned char*)(Psm + bo) = f2e4m3(pv);
        }
    }
    asm volatile("s_waitcnt lgkmcnt(0)" ::: "memory");
    __builtin_amdgcn_sched_barrier(0);

    // O += P · V (fp8): one b128 per operand pair feeds two MFMAs (js=0,1).
    const long long ones8 = 0x3838383838383838LL;   // e4m3 1.0 x8
    __builtin_amdgcn_s_setprio(1);
    {
        int pr = l & 15;
        llx2 pa01 = *(const llx2*)(Psm + pr * 64 +
                     ((((l >> 4)) ^ ((pr >> 1) & 3)) << 4));
        #pragma unroll
        for (int sub = 0; sub < 16; ++sub) {
            int d = sub * 16 + (l & 15);
            int dp = d >> 1, h = d & 1;
            llx2 vb01 = *(const llx2*)(Vsm + dp * 128 +
                         ((h * 4 + ((l >> 4) ^ (dp & 3))) << 4));
            st.acc[sub] = mfma8(pa01[0], vb01[0], st.acc[sub]);
            st.acc[sub] = mfma8(pa01[1], vb01[1], st.acc[sub]);
        }
        st.accSum = mfma8(pa01[0], ones8, st.accSum);
        st.accSum = mfma8(pa01[1], ones8, st.accSum);
    }
    __builtin_amdgcn_s_setprio(0);
}

#define ATTN_STAGE(KN, VN, kvn)                                                   \
    do {                                                                          \
        _Pragma("unroll")                                                         \
        for (int i_ = 0; i_ < 2; ++i_) {      /* K fp8: 16KB, rows 256B */        \
            int e_ = (w * 2 + i_) * 64 + l;                                       \
            int r_ = e_ >> 4, p_ = e_ & 15;                                       \
            gload16(kg8 + (size_t)((kvn) + r_) * 512 + ((p_ ^ (r_ & 7)) * 16),    \
                    (KN) + (w * 2 + i_) * 1024);                                  \
        }                                                                         \
        _Pragma("unroll")                                                         \
        for (int i_ = 0; i_ < 2; ++i_) {      /* V fp8: 16KB, d-paired 128B */    \
            int e_ = (w * 2 + i_) * 64 + l;                                       \
            int dp_ = e_ >> 3, c_ = e_ & 7;                                       \
            int h_ = c_ >> 2, g_ = (c_ & 3) ^ (dp_ & 3);                          \
            gload16(vg8 + (size_t)(2 * dp_ + h_) * 4096 + (kvn) + g_ * 16,        \
                    (VN) + (w * 2 + i_) * 1024);                                  \
        }                                                                         \
    } while (0)

__global__ __launch_bounds__(512, 2) void k_attn(const unsigned char* __restrict__ qk8,
        const unsigned char* __restrict__ vT8, unsigned short* __restrict__ Opart,
        float* __restrict__ ml) {
    __shared__ __align__(16) char smem[73728];
    char* Ksm0 = smem;
    char* Vsm0 = smem + 16384;
    char* Ksm1 = smem + 32768;
    char* Vsm1 = smem + 49152;
    int t = threadIdx.x, l = t & 63, w = t >> 6;   // w in 0..7
    char* Psm = smem + 65536 + w * 1024;           // per-wave P 16x64 fp8
    int bid = blockIdx.x;
    int combo = bid & 7;
    int b = combo >> 1;
    int half = combo & 1;
    int qb = (bid >> 3) * 128;
    int kv0 = half * 2048;

    const unsigned char* qrow8 = qk8 + (size_t)(b * 4096 + qb + w * 16 + (l & 15)) * 512;
    long long qf8[8];
    #pragma unroll
    for (int ks = 0; ks < 8; ++ks)
        qf8[ks] = *(const long long*)(qrow8 + ks * 32 + (l >> 4) * 8);

    AttnState st;
    #pragma unroll
    for (int i = 0; i < 16; ++i) st.acc[i] = f32x4{0.f, 0.f, 0.f, 0.f};
    st.accSum = f32x4{0.f, 0.f, 0.f, 0.f};
    #pragma unroll
    for (int r = 0; r < 4; ++r) st.m_run[r] = -3.0e38f;

    const unsigned char* kg8 = qk8 + (size_t)(b * 4096) * 512 + 256;
    const unsigned char* vg8 = vT8 + (size_t)(b * 256) * 4096;

    ATTN_STAGE(Ksm0, Vsm0, kv0);
    __syncthreads();

    for (int kv = kv0; kv < kv0 + 2048; kv += 128) {
        ATTN_STAGE(Ksm1, Vsm1, kv + 64);
        attn_compute(Ksm0, Vsm0, Psm, qf8, st, l);
        __syncthreads();   // buf1 staged; buf0 reads done block-wide
        int kvn2 = (kv + 128 < kv0 + 2048) ? (kv + 128) : kv0;  // last: harmless re-stage
        ATTN_STAGE(Ksm0, Vsm0, kvn2);
        attn_compute(Ksm1, Vsm1, Psm, qf8, st, l);
        __syncthreads();
    }

    float inv[4];
    #pragma unroll
    for (int r = 0; r < 4; ++r) inv[r] = 1.f / st.accSum[r];
    unsigned short* orow = Opart + (size_t)half * 16384 * 256 +
                           (size_t)(b * 4096 + qb + w * 16) * 256;
    #pragma unroll
    for (int sub = 0; sub < 16; ++sub) {
        #pragma unroll
        for (int r = 0; r < 4; ++r)
            orow[(size_t)((l >> 4) * 4 + r) * 256 + sub * 16 + (l & 15)] = f2bf(st.acc[sub][r] * inv[r]);
    }
    if ((l & 15) == 0) {
        size_t mlbase = (size_t)(b * 4096 + qb + w * 16 + (l >> 4) * 4) * 4;
        #pragma unroll
        for (int r = 0; r < 4; ++r) {
            ml[mlbase + (size_t)r * 4 + half * 2]     = st.m_run[r];
            ml[mlbase + (size_t)r * 4 + half * 2 + 1] = st.accSum[r];
        }
    }
}

// ---------------------------------------------------------------------------
// K6: proj GEMM + FUSED kv-half combine + bias + residual (recomputed GN).
// ---------------------------------------------------------------------------
__global__ __launch_bounds__(256) void k_proj(const unsigned short* __restrict__ Opart,
        const float* __restrict__ ml, const unsigned short* __restrict__ wp,
        const float* __restrict__ bproj, const float* __restrict__ x,
        const float* __restrict__ nscale, const float* __restrict__ nbias,
        const float* __restrict__ stats, float* __restrict__ out) {
    __shared__ __align__(16) char smem[65536];
    char* Asm = smem;
    char* Bsm = smem + 32768;
    int t = threadIdx.x, l = t & 63, w = t >> 6;
    int mb = blockIdx.x * 64, nb = blockIdx.y * 64;
    #pragma unroll
    for (int i = 0; i < 8; ++i) {
        int idx = (w * 8 + i) * 64 + l;
        int r = idx >> 5, p = idx & 31;
        size_t grow = (size_t)(mb + r);
        const u16x8* o1p = (const u16x8*)(Opart + grow * 256 + ((p ^ (r & 7)) * 8));
        const u16x8* o2p = (const u16x8*)((const unsigned short*)o1p + (size_t)16384 * 256);
        float m1 = ml[grow * 4],     l1 = ml[grow * 4 + 1];
        float m2 = ml[grow * 4 + 2], l2 = ml[grow * 4 + 3];
        float m = fmaxf(m1, m2);
        float a1 = __builtin_amdgcn_exp2f(m1 - m) * l1;
        float a2 = __builtin_amdgcn_exp2f(m2 - m) * l2;
        float zinv = 1.f / (a1 + a2);
        float w1 = a1 * zinv, w2 = a2 * zinv;
        u16x8 o1 = *o1p, o2 = *o2p, a;
        #pragma unroll
        for (int j = 0; j < 8; ++j) a[j] = f2bf(w1 * bf2f(o1[j]) + w2 * bf2f(o2[j]));
        *(u16x8*)(Asm + (w * 8 + i) * 1024 + l * 16) = a;
    }
    #pragma unroll
    for (int i = 0; i < 8; ++i) {
        int idx = (w * 8 + i) * 64 + l;
        int r = idx >> 5, p = idx & 31;
        gload16(wp + (size_t)(nb + r) * 256 + ((p ^ (r & 7)) * 8), Bsm + (w * 8 + i) * 1024);
    }
    __syncthreads();
    int arow = w * 16 + (l & 15);
    bf16x8 af[8];
    #pragma unroll
    for (int ks = 0; ks < 8; ++ks)
        af[ks] = *(const bf16x8*)(Asm + arow * 512 + (((ks * 4 + (l >> 4)) ^ (arow & 7)) << 4));
    f32x4 acc[4];
    #pragma unroll
    for (int i = 0; i < 4; ++i) acc[i] = f32x4{0.f, 0.f, 0.f, 0.f};
    #pragma unroll
    for (int sub = 0; sub < 4; ++sub) {
        int brow = sub * 16 + (l & 15);
        #pragma unroll
        for (int ks = 0; ks < 8; ++ks) {
            bf16x8 bb = *(const bf16x8*)(Bsm + brow * 512 + (((ks * 4 + (l >> 4)) ^ (brow & 7)) << 4));
            acc[sub] = mfma16(af[ks], bb, acc[sub]);
        }
    }
    __syncthreads();  // all waves done reading A/B tiles; reuse LDS for transpose
    float* tr = (float*)smem;  // [64][68] f32
    #pragma unroll
    for (int sub = 0; sub < 4; ++sub) {
        int o = sub * 16 + (l & 15);
        *(f32x4*)(tr + o * 68 + w * 16 + (l >> 4) * 4) = acc[sub];
    }
    __syncthreads();
    int b = mb >> 12;
    int nloc = mb & 4095;
    #pragma unroll
    for (int it = 0; it < 4; ++it) {
        int e = it * 256 + t;
        int o = e >> 4, m4 = (e & 15) * 4;
        f32x4 v = *(const f32x4*)(tr + o * 68 + m4);
        int c = nb + o;
        float bv = bproj[c];
        float mean = stats[(b * 32 + (c >> 3)) * 2];
        float rstd = stats[(b * 32 + (c >> 3)) * 2 + 1];
        float sc = nscale[c] * rstd;
        float bi = nbias[c] - mean * sc;
        size_t off = ((size_t)(b * 256 + c)) * 4096 + nloc + m4;
        float4 xx = *(const float4*)(x + off);
        float4 ov;
        ov.x = v[0] + bv + (xx.x * sc + bi);
        ov.y = v[1] + bv + (xx.y * sc + bi);
        ov.z = v[2] + bv + (xx.z * sc + bi);
        ov.w = v[3] + bv + (xx.w * sc + bi);
        *(float4*)(out + off) = ov;
    }
}

// ---------------------------------------------------------------------------
extern "C" void kernel_launch(void* const* d_in, const int* in_sizes, int n_in,
                              void* d_out, int out_size, void* d_ws, size_t ws_size,
                              hipStream_t stream) {
    const float* x      = (const float*)d_in[0];
    const float* nscale = (const float*)d_in[1];
    const float* nbias  = (const float*)d_in[2];
    const float* wqkv   = (const float*)d_in[3];
    const float* wproj  = (const float*)d_in[4];
    const float* bproj  = (const float*)d_in[5];
    float* out = (float*)d_out;

    char* ws = (char*)d_ws;
    float* stats = (float*)ws;                                        // 4 KB
    unsigned short* xnT = (unsigned short*)(ws + 4096);               // 8 MB bf16 (b,n,c)
    unsigned short* wq  = xnT + 4194304;                              // 384 KB
    unsigned short* wp  = wq + 768 * 256;                             // 128 KB
    unsigned char* vT8  = (unsigned char*)(wp + 256 * 256);           // 4 MB fp8 (b,d,perm-kv)
    float* ml = (float*)(vT8 + (size_t)4 * 256 * 4096);               // 256 KB
    unsigned char* qk8 = (unsigned char*)(ml + 65536);                // 8 MB fp8 (b,n,512): q|k
    unsigned short* Opart = (unsigned short*)(qk8 + (size_t)16384 * 512); // 16 MB bf16 (2,16384,256)

    hipLaunchKernelGGL(k_pre,     dim3(1152),       dim3(256), 0, stream, wqkv, wproj, x, wq, wp, stats);
    hipLaunchKernelGGL(k_gnapply, dim3(64, 4, 4),   dim3(256), 0, stream, x, nscale, nbias, stats, xnT);
    hipLaunchKernelGGL(k_qkv,     dim3(256, 6),     dim3(256), 0, stream, xnT, wq, qk8, vT8);
    hipLaunchKernelGGL(k_attn,    dim3(256),        dim3(512), 0, stream, qk8, vT8, Opart, ml);
    hipLaunchKernelGGL(k_proj,    dim3(256, 4),     dim3(256), 0, stream, Opart, ml, wp, bproj, x, nscale, nbias, stats, out);
}